// Round 7
// baseline (2763.276 us; speedup 1.0000x reference)
//
#include <hip/hip_runtime.h>
#include <cstdint>

#define N_NODES 100000
#define N_EDGES 1600000
#define R_REL   5
#define NBASIS  2
#define B_START 512
#define PART_SZ 12500          // 8 * 12500 = 100000
#define HALF_P  6250
#define ARENA_CAP 262144       // per-partition capacity (mean 200K, sd ~420)

__device__ __forceinline__ unsigned short f2bf(float f) {
    unsigned u = __float_as_uint(f);
    unsigned r = (u + 0x7FFF + ((u >> 16) & 1)) >> 16;  // RNE
    return (unsigned short)r;
}

// ---------------- CSR build ----------------

__global__ void k_zero_int(int* p, int n) {
    int i = blockIdx.x * blockDim.x + threadIdx.x;
    if (i < n) p[i] = 0;
}

// Phase 1: 8-way bucket by dst partition. Wave-level ballot ranking — no LDS.
// Each wave contributes ~8 consecutive arena slots per partition (~1 line).
__global__ __launch_bounds__(256) void k_bin(
    const int* __restrict__ ei, const int* __restrict__ et,
    int2* __restrict__ arena, int* __restrict__ gcur) {
    int e = blockIdx.x * 256 + threadIdx.x;   // grid covers exactly N_EDGES
    int src = ei[e];
    int dst = ei[N_EDGES + e];
    int t   = et[e];
    int part = dst / PART_SZ;
    int2 rec = make_int2(src | (t << 20), dst);
    int lane = threadIdx.x & 63;
    unsigned long long lmask = (lane == 63) ? 0x7FFFFFFFFFFFFFFFull
                                            : ((1ull << lane) - 1ull);
    int pos = 0;
#pragma unroll
    for (int p = 0; p < 8; p++) {
        unsigned long long mask = __ballot(part == p);
        if (part == p) {
            int rank   = __popcll(mask & lmask);
            int leader = __ffsll(mask) - 1;
            int base = 0;
            if (rank == 0) base = atomicAdd(&gcur[p], __popcll(mask));
            base = __shfl(base, leader, 64);
            pos = base + rank;
        }
    }
    arena[(size_t)part * ARENA_CAP + pos] = rec;
}

// Phase 2a: per-partition histogram. cnt slice (250KB) stays L2-resident;
// arena stream read non-temporally to avoid evicting it.
__global__ __launch_bounds__(256) void k_hist_p(
    const int2* __restrict__ arena, const int* __restrict__ gcur,
    int* __restrict__ cnt) {
    int part = blockIdx.x & 7;
    int bid  = blockIdx.x >> 3;
    int nb   = gridDim.x >> 3;
    int count = gcur[part];
    const long long* ar = (const long long*)(arena + (size_t)part * ARENA_CAP);
    for (int i = bid * 256 + threadIdx.x; i < count; i += nb * 256) {
        long long v = __builtin_nontemporal_load(&ar[i]);
        int x   = (int)v;
        int dst = (int)(v >> 32);
        int t   = ((unsigned)x) >> 20;
        atomicAdd(&cnt[dst * R_REL + t], 1);
    }
}

// local scan over node degrees + per-(node,rel) mean norm
__global__ void k_scan1(const int* __restrict__ cnt, int* __restrict__ off,
                        int* __restrict__ bsum, float* __restrict__ normf) {
    __shared__ int s[256];
    int t = threadIdx.x;
    int n = blockIdx.x * 256 + t;
    int deg = 0;
    if (n < N_NODES) {
#pragma unroll
        for (int r = 0; r < R_REL; r++) {
            int c = cnt[n * R_REL + r];
            deg += c;
            normf[n * R_REL + r] = 1.0f / (float)(c > 0 ? c : 1);
        }
    }
    s[t] = deg;
    __syncthreads();
    for (int o = 1; o < 256; o <<= 1) {
        int v = (t >= o) ? s[t - o] : 0;
        __syncthreads();
        s[t] += v;
        __syncthreads();
    }
    if (n < N_NODES) off[n] = s[t] - deg;
    if (t == 255) bsum[blockIdx.x] = s[t];
}

__global__ void k_scan2(int* bsum, int nb) {
    __shared__ int s[512];
    int t = threadIdx.x;
    int v = (t < nb) ? bsum[t] : 0;
    s[t] = v;
    __syncthreads();
    for (int o = 1; o < 512; o <<= 1) {
        int u = (t >= o) ? s[t - o] : 0;
        __syncthreads();
        s[t] += u;
        __syncthreads();
    }
    if (t < nb) bsum[t] = s[t] - v;
}

__global__ void k_scan3(int* __restrict__ off, int* __restrict__ cur,
                        const int* __restrict__ bsum) {
    int t = threadIdx.x;
    int n = blockIdx.x * 256 + t;
    if (n < N_NODES) {
        int v = off[n] + bsum[blockIdx.x];
        off[n] = v;
        cur[n] = v;
    }
    if (n == 0) off[N_NODES] = N_EDGES;
}

// Phase 2b: per-partition CSR fill. packed slice (1.6MB), cur (50KB) and
// normf (250KB) slices L2-resident; arena read non-temporal.
__global__ __launch_bounds__(256) void k_fill_p(
    const int2* __restrict__ arena, const int* __restrict__ gcur,
    int* __restrict__ cur, int2* __restrict__ packed,
    const float* __restrict__ normf) {
    int part = blockIdx.x & 7;
    int bid  = blockIdx.x >> 3;
    int nb   = gridDim.x >> 3;
    int count = gcur[part];
    const long long* ar = (const long long*)(arena + (size_t)part * ARENA_CAP);
    for (int i = bid * 256 + threadIdx.x; i < count; i += nb * 256) {
        long long v = __builtin_nontemporal_load(&ar[i]);
        int x   = (int)v;
        int dst = (int)(v >> 32);
        int t   = ((unsigned)x) >> 20;
        int slot = atomicAdd(&cur[dst], 1);
        float nv = normf[dst * R_REL + t];
        packed[slot] = make_int2(x, __float_as_int(nv));
    }
}

// ---------------- per-layer node transform ---------------------------------
// y5[r][n][c] = bf16( comp[r,0]*(h@B0) + comp[r,1]*(h@B1) )   (5 planes)
// h := h@root + bias   (in-place per-row, race-free)

template <int IN>
__global__ __launch_bounds__(256) void k_xform(
    const float* __restrict__ h_in, float* __restrict__ h_io,
    unsigned short* __restrict__ y5, const float* __restrict__ basis,
    const float* __restrict__ root, const float* __restrict__ biasL,
    const float* __restrict__ compL) {
    int tid  = threadIdx.x;
    int lane = tid & 31;
    int sub  = tid >> 5;
    int g    = blockIdx.x * 8 + sub;   // 1024 blocks * 8 = 8192 groups
    float w0[IN], w1[IN], wr[IN];
#pragma unroll
    for (int i = 0; i < IN; i++) {
        w0[i] = basis[i * 32 + lane];
        w1[i] = basis[IN * 32 + i * 32 + lane];
        wr[i] = root[i * 32 + lane];
    }
    float c0[R_REL], c1[R_REL];
#pragma unroll
    for (int r = 0; r < R_REL; r++) {
        c0[r] = compL[r * NBASIS + 0];
        c1[r] = compL[r * NBASIS + 1];
    }
    float bv = biasL[lane];
    for (int n = g; n < N_NODES; n += 8192) {
        float hn = (lane < IN) ? h_in[n * IN + lane] : 0.f;
        float a0 = 0.f, a1 = 0.f, ar = bv;
#pragma unroll
        for (int i = 0; i < IN; i++) {
            float v = __shfl(hn, i, 32);
            a0 += v * w0[i];
            a1 += v * w1[i];
            ar += v * wr[i];
        }
#pragma unroll
        for (int r = 0; r < R_REL; r++)
            y5[(size_t)r * N_NODES * 32 + n * 32 + lane] = f2bf(c0[r] * a0 + c1[r] * a1);
        h_io[n * 32 + lane] = ar;
    }
}

// ---------------- edge aggregation --------------------------------------
// Two nodes per half-wave (n, n+6250) -> 16 independent gathers in flight.
// Pad lanes carry m=0, nv=0 -> gather row 0 (L1-hot) times zero: exact.

__global__ __launch_bounds__(256) void k_edge(
    const unsigned short* __restrict__ y5, float* __restrict__ h,
    const int2* __restrict__ packed, const int* __restrict__ off) {
    int tid  = threadIdx.x;
    int lane = tid & 31;
    int sub  = tid >> 5;
    int part  = blockIdx.x & 7;
    int local = (blockIdx.x >> 3) * 8 + sub;
    if (local >= HALF_P) return;
    int nA = part * PART_SZ + local;
    int nB = nA + HALF_P;

    float accA = h[nA * 32 + lane];
    float accB = h[nB * 32 + lane];
    int a0 = off[nA], a1 = off[nA + 1];
    int b0 = off[nB], b1 = off[nB + 1];

    for (int baseA = a0, baseB = b0; baseA < a1 || baseB < b1;
         baseA += 32, baseB += 32) {
        int idxA = baseA + lane;
        int idxB = baseB + lane;
        int2 pkA = (idxA < a1) ? packed[idxA] : make_int2(0, 0);
        int2 pkB = (idxB < b1) ? packed[idxB] : make_int2(0, 0);
        int   mA = pkA.x;  float nvA = __int_as_float(pkA.y);
        int   mB = pkB.x;  float nvB = __int_as_float(pkB.y);
        int kA = a1 - baseA; kA = kA < 0 ? 0 : (kA > 32 ? 32 : kA);
        int kB = b1 - baseB; kB = kB < 0 ? 0 : (kB > 32 ? 32 : kB);
        int kkA = (kA + 7) & ~7, kkB = (kB + 7) & ~7;
        int kk = kkA > kkB ? kkA : kkB;
        for (int j = 0; j < kk; j += 8) {
#pragma unroll
            for (int q = 0; q < 2; q++) {
                int   m  = q ? mB : mA;
                float nv = q ? nvB : nvA;
                int m0 = __shfl(m, j + 0, 32), m1 = __shfl(m, j + 1, 32);
                int m2 = __shfl(m, j + 2, 32), m3 = __shfl(m, j + 3, 32);
                int m4 = __shfl(m, j + 4, 32), m5 = __shfl(m, j + 5, 32);
                int m6 = __shfl(m, j + 6, 32), m7 = __shfl(m, j + 7, 32);
                unsigned r0 = ((unsigned)m0 >> 20) * N_NODES + (m0 & 0xFFFFF);
                unsigned r1 = ((unsigned)m1 >> 20) * N_NODES + (m1 & 0xFFFFF);
                unsigned r2 = ((unsigned)m2 >> 20) * N_NODES + (m2 & 0xFFFFF);
                unsigned r3 = ((unsigned)m3 >> 20) * N_NODES + (m3 & 0xFFFFF);
                unsigned r4 = ((unsigned)m4 >> 20) * N_NODES + (m4 & 0xFFFFF);
                unsigned r5 = ((unsigned)m5 >> 20) * N_NODES + (m5 & 0xFFFFF);
                unsigned r6 = ((unsigned)m6 >> 20) * N_NODES + (m6 & 0xFFFFF);
                unsigned r7 = ((unsigned)m7 >> 20) * N_NODES + (m7 & 0xFFFFF);
                unsigned short u0 = y5[(size_t)r0 * 32 + lane];
                unsigned short u1 = y5[(size_t)r1 * 32 + lane];
                unsigned short u2 = y5[(size_t)r2 * 32 + lane];
                unsigned short u3 = y5[(size_t)r3 * 32 + lane];
                unsigned short u4 = y5[(size_t)r4 * 32 + lane];
                unsigned short u5 = y5[(size_t)r5 * 32 + lane];
                unsigned short u6 = y5[(size_t)r6 * 32 + lane];
                unsigned short u7 = y5[(size_t)r7 * 32 + lane];
                float v0 = __shfl(nv, j + 0, 32), v1 = __shfl(nv, j + 1, 32);
                float v2 = __shfl(nv, j + 2, 32), v3 = __shfl(nv, j + 3, 32);
                float v4 = __shfl(nv, j + 4, 32), v5 = __shfl(nv, j + 5, 32);
                float v6 = __shfl(nv, j + 6, 32), v7 = __shfl(nv, j + 7, 32);
                float s = 0.f;
                s += v0 * __uint_as_float((unsigned)u0 << 16);
                s += v1 * __uint_as_float((unsigned)u1 << 16);
                s += v2 * __uint_as_float((unsigned)u2 << 16);
                s += v3 * __uint_as_float((unsigned)u3 << 16);
                s += v4 * __uint_as_float((unsigned)u4 << 16);
                s += v5 * __uint_as_float((unsigned)u5 << 16);
                s += v6 * __uint_as_float((unsigned)u6 << 16);
                s += v7 * __uint_as_float((unsigned)u7 << 16);
                if (q) accB += s; else accA += s;
            }
        }
    }
    h[nA * 32 + lane] = tanhf(accA);
    h[nB * 32 + lane] = tanhf(accB);
}

// ---------------- start-node row save + MLP head ----------------

__global__ void k_save(const float* __restrict__ h, const int* __restrict__ start,
                       float* __restrict__ sav) {
    int t = blockIdx.x * blockDim.x + threadIdx.x;
    if (t < B_START * 32) {
        int b = t >> 5, ln = t & 31;
        sav[t] = h[start[b] * 32 + ln];
    }
}

__global__ __launch_bounds__(128) void k_mlp(
    const float* __restrict__ sav, const float* __restrict__ w1,
    const float* __restrict__ b1, const float* __restrict__ w2,
    const float* __restrict__ b2, float* __restrict__ out) {
    __shared__ float cvec[128];
    __shared__ float hb[128];
    __shared__ float lg[8];
    int b = blockIdx.x, t = threadIdx.x;
    cvec[t] = sav[(t >> 5) * (B_START * 32) + b * 32 + (t & 31)];
    __syncthreads();
    float a = b1[t];
#pragma unroll 8
    for (int k = 0; k < 128; k++) a += cvec[k] * w1[k * 128 + t];
    hb[t] = fmaxf(a, 0.f);
    __syncthreads();
    if (t < 5) {
        float a2 = b2[t];
        for (int k = 0; k < 128; k++) a2 += hb[k] * w2[k * 5 + t];
        lg[t] = a2;
    }
    __syncthreads();
    if (t < 5) {
        float m = lg[0];
        for (int j = 1; j < 5; j++) m = fmaxf(m, lg[j]);
        float s = 0.f;
        for (int j = 0; j < 5; j++) s += expf(lg[j] - m);
        out[b * 5 + t] = lg[t] - m - logf(s);
    }
}

// ---------------- launch ----------------

extern "C" void kernel_launch(void* const* d_in, const int* in_sizes, int n_in,
                              void* d_out, int out_size, void* d_ws, size_t ws_size,
                              hipStream_t stream) {
    const float* x      = (const float*)d_in[0];
    const int*   ei     = (const int*)d_in[1];
    const int*   etype  = (const int*)d_in[2];
    const int*   start  = (const int*)d_in[3];
    const float* basis0 = (const float*)d_in[4];
    const float* comp0  = (const float*)d_in[5];
    const float* root0  = (const float*)d_in[6];
    const float* bias0  = (const float*)d_in[7];
    const float* basis  = (const float*)d_in[8];
    const float* comp   = (const float*)d_in[9];
    const float* root   = (const float*)d_in[10];
    const float* bias   = (const float*)d_in[11];
    const float* w1     = (const float*)d_in[12];
    const float* b1     = (const float*)d_in[13];
    const float* w2     = (const float*)d_in[14];
    const float* b2     = (const float*)d_in[15];
    float* out = (float*)d_out;

    char* p = (char*)d_ws;
    auto alloc = [&](size_t bytes) -> void* {
        void* r = (void*)p;
        p += (bytes + 255) & ~(size_t)255;
        return r;
    };
    int*            off    = (int*)alloc((N_NODES + 1) * 4);
    int*            cur    = (int*)alloc(N_NODES * 4);
    int*            cnt    = (int*)alloc((N_NODES * R_REL + 8) * 4);  // +8 = gcur
    int*            gcur   = cnt + N_NODES * R_REL;
    int2*           arena  = (int2*)alloc((size_t)8 * ARENA_CAP * 8);
    int2*           packed = (int2*)alloc((size_t)N_EDGES * 8);
    int*            bsum   = (int*)alloc(512 * 4);
    float*          normf  = (float*)alloc(N_NODES * R_REL * 4);
    float*          h      = (float*)alloc((size_t)N_NODES * 32 * 4);
    unsigned short* y5     = (unsigned short*)alloc((size_t)R_REL * N_NODES * 32 * 2);
    float*          sav    = (float*)alloc(4 * B_START * 32 * 4);

    int nbScan = (N_NODES + 255) / 256;  // 391

    k_zero_int<<<(N_NODES * R_REL + 8 + 255) / 256, 256, 0, stream>>>(cnt, N_NODES * R_REL + 8);
    k_bin<<<N_EDGES / 256, 256, 0, stream>>>(ei, etype, arena, gcur);
    k_hist_p<<<8 * 104, 256, 0, stream>>>(arena, gcur, cnt);
    k_scan1<<<nbScan, 256, 0, stream>>>(cnt, off, bsum, normf);
    k_scan2<<<1, 512, 0, stream>>>(bsum, nbScan);
    k_scan3<<<nbScan, 256, 0, stream>>>(off, cur, bsum);
    k_fill_p<<<8 * 104, 256, 0, stream>>>(arena, gcur, cur, packed, normf);

    int nbEdge = 8 * ((HALF_P + 7) / 8);  // 8 * 782 = 6256 blocks
    // layer 0 (in=4)
    k_xform<4><<<1024, 256, 0, stream>>>(x, h, y5, basis0, root0, bias0, comp0);
    k_edge<<<nbEdge, 256, 0, stream>>>(y5, h, packed, off);
    k_save<<<64, 256, 0, stream>>>(h, start, sav);
    // layers 1..3 (in=32)
    for (int l = 0; l < 3; l++) {
        k_xform<32><<<1024, 256, 0, stream>>>(h, h, y5,
                                              basis + (size_t)l * 2048,
                                              root + (size_t)l * 1024,
                                              bias + l * 32,
                                              comp + l * 10);
        k_edge<<<nbEdge, 256, 0, stream>>>(y5, h, packed, off);
        k_save<<<64, 256, 0, stream>>>(h, start, sav + (l + 1) * 16384);
    }

    k_mlp<<<B_START, 128, 0, stream>>>(sav, w1, b1, w2, b2, out);
}

// Round 8
// 527.764 us; speedup vs baseline: 5.2358x; 5.2358x over previous
//
#include <hip/hip_runtime.h>
#include <cstdint>

#define N_NODES 100000
#define N_EDGES 1600000
#define R_REL   5
#define NBASIS  2
#define B_START 512
#define PART_SZ 12500          // 8 * 12500 = 100000
#define ARENA_CAP 262144       // per-partition capacity (mean 200K, sd ~420)
#define NB_BIN  6250           // N_EDGES / 256

__device__ __forceinline__ unsigned short f2bf(float f) {
    unsigned u = __float_as_uint(f);
    unsigned r = (u + 0x7FFF + ((u >> 16) & 1)) >> 16;  // RNE
    return (unsigned short)r;
}

// ---------------- CSR build ----------------

__global__ void k_zero_int(int* p, int n) {
    int i = blockIdx.x * blockDim.x + threadIdx.x;
    if (i < n) p[i] = 0;
}

// Phase 1a: per-block 8-bucket histogram (ballot count, no global atomics).
__global__ __launch_bounds__(256) void k_cnt8(
    const int* __restrict__ ei, int* __restrict__ bhist) {
    __shared__ int lh[8];
    int tid = threadIdx.x;
    if (tid < 8) lh[tid] = 0;
    __syncthreads();
    int e = blockIdx.x * 256 + tid;
    int part = ei[N_EDGES + e] / PART_SZ;
    int lane = tid & 63;
#pragma unroll
    for (int p = 0; p < 8; p++) {
        unsigned long long m = __ballot(part == p);
        if (lane == 0) atomicAdd(&lh[p], (int)__popcll(m));
    }
    __syncthreads();
    if (tid < 8) bhist[tid * NB_BIN + blockIdx.x] = lh[tid];
}

// Phase 1b: exclusive scan of block counts per bucket; totals -> gcur.
__global__ __launch_bounds__(256) void k_scan8(
    int* __restrict__ bhist, int* __restrict__ gcur) {
    __shared__ int s[256];
    int p = blockIdx.x, t = threadIdx.x;
    int carry = 0;
    for (int c = 0; c < NB_BIN; c += 256) {
        int i = c + t;
        int v = (i < NB_BIN) ? bhist[p * NB_BIN + i] : 0;
        s[t] = v;
        __syncthreads();
        for (int o = 1; o < 256; o <<= 1) {
            int u = (t >= o) ? s[t - o] : 0;
            __syncthreads();
            s[t] += u;
            __syncthreads();
        }
        int incl = s[t];
        int tot  = s[255];
        if (i < NB_BIN) bhist[p * NB_BIN + i] = carry + incl - v;  // exclusive
        carry += tot;
        __syncthreads();
    }
    if (t == 0) gcur[p] = carry;
}

// Phase 1c: deterministic scatter into arenas (ballot rank + LDS wave prefix).
__global__ __launch_bounds__(256) void k_scat8(
    const int* __restrict__ ei, const int* __restrict__ et,
    const int* __restrict__ bhist, int2* __restrict__ arena) {
    __shared__ int wcnt[4][8];
    __shared__ int wpref[4][8];
    int tid = threadIdx.x, w = tid >> 6, lane = tid & 63;
    int e = blockIdx.x * 256 + tid;
    int src = ei[e];
    int dst = ei[N_EDGES + e];
    int t   = et[e];
    int part = dst / PART_SZ;
    unsigned long long lmask = (1ull << lane) - 1ull;
    int rank = 0;
#pragma unroll
    for (int p = 0; p < 8; p++) {
        unsigned long long m = __ballot(part == p);
        if (lane == 0) wcnt[w][p] = (int)__popcll(m);
        if (part == p) rank = (int)__popcll(m & lmask);
    }
    __syncthreads();
    if (tid < 32) {
        int w2 = tid >> 3, p2 = tid & 7, sum = 0;
        for (int w3 = 0; w3 < w2; w3++) sum += wcnt[w3][p2];
        wpref[w2][p2] = sum;
    }
    __syncthreads();
    int base = bhist[part * NB_BIN + blockIdx.x];
    int pos = base + wpref[w][part] + rank;
    arena[(size_t)part * ARENA_CAP + pos] = make_int2(src | (t << 20), dst);
}

// Phase 2a: per-partition histogram. cnt slice (250KB) stays L2-resident;
// arena stream read non-temporally to avoid evicting it.
__global__ __launch_bounds__(256) void k_hist_p(
    const int2* __restrict__ arena, const int* __restrict__ gcur,
    int* __restrict__ cnt) {
    int part = blockIdx.x & 7;
    int bid  = blockIdx.x >> 3;
    int nb   = gridDim.x >> 3;
    int count = gcur[part];
    const long long* ar = (const long long*)(arena + (size_t)part * ARENA_CAP);
    for (int i = bid * 256 + threadIdx.x; i < count; i += nb * 256) {
        long long v = __builtin_nontemporal_load(&ar[i]);
        int x   = (int)v;
        int dst = (int)(v >> 32);
        int t   = ((unsigned)x) >> 20;
        atomicAdd(&cnt[dst * R_REL + t], 1);
    }
}

// local scan over node degrees + per-(node,rel) mean norm
__global__ void k_scan1(const int* __restrict__ cnt, int* __restrict__ off,
                        int* __restrict__ bsum, float* __restrict__ normf) {
    __shared__ int s[256];
    int t = threadIdx.x;
    int n = blockIdx.x * 256 + t;
    int deg = 0;
    if (n < N_NODES) {
#pragma unroll
        for (int r = 0; r < R_REL; r++) {
            int c = cnt[n * R_REL + r];
            deg += c;
            normf[n * R_REL + r] = 1.0f / (float)(c > 0 ? c : 1);
        }
    }
    s[t] = deg;
    __syncthreads();
    for (int o = 1; o < 256; o <<= 1) {
        int v = (t >= o) ? s[t - o] : 0;
        __syncthreads();
        s[t] += v;
        __syncthreads();
    }
    if (n < N_NODES) off[n] = s[t] - deg;
    if (t == 255) bsum[blockIdx.x] = s[t];
}

__global__ void k_scan2(int* bsum, int nb) {
    __shared__ int s[512];
    int t = threadIdx.x;
    int v = (t < nb) ? bsum[t] : 0;
    s[t] = v;
    __syncthreads();
    for (int o = 1; o < 512; o <<= 1) {
        int u = (t >= o) ? s[t - o] : 0;
        __syncthreads();
        s[t] += u;
        __syncthreads();
    }
    if (t < nb) bsum[t] = s[t] - v;
}

__global__ void k_scan3(int* __restrict__ off, int* __restrict__ cur,
                        const int* __restrict__ bsum) {
    int t = threadIdx.x;
    int n = blockIdx.x * 256 + t;
    if (n < N_NODES) {
        int v = off[n] + bsum[blockIdx.x];
        off[n] = v;
        cur[n] = v;
    }
    if (n == 0) off[N_NODES] = N_EDGES;
}

// Phase 2b: per-partition CSR fill. packed slice (1.6MB), cur and normf
// slices L2-resident; arena read non-temporal.
__global__ __launch_bounds__(256) void k_fill_p(
    const int2* __restrict__ arena, const int* __restrict__ gcur,
    int* __restrict__ cur, int2* __restrict__ packed,
    const float* __restrict__ normf) {
    int part = blockIdx.x & 7;
    int bid  = blockIdx.x >> 3;
    int nb   = gridDim.x >> 3;
    int count = gcur[part];
    const long long* ar = (const long long*)(arena + (size_t)part * ARENA_CAP);
    for (int i = bid * 256 + threadIdx.x; i < count; i += nb * 256) {
        long long v = __builtin_nontemporal_load(&ar[i]);
        int x   = (int)v;
        int dst = (int)(v >> 32);
        int t   = ((unsigned)x) >> 20;
        int slot = atomicAdd(&cur[dst], 1);
        float nv = normf[dst * R_REL + t];
        packed[slot] = make_int2(x, __float_as_int(nv));
    }
}

// ---------------- per-layer node transform ---------------------------------
// y5[r][n][c] = bf16( comp[r,0]*(h@B0) + comp[r,1]*(h@B1) )   (5 planes)
// h := h@root + bias   (in-place per-row, race-free)

template <int IN>
__global__ __launch_bounds__(256) void k_xform(
    const float* __restrict__ h_in, float* __restrict__ h_io,
    unsigned short* __restrict__ y5, const float* __restrict__ basis,
    const float* __restrict__ root, const float* __restrict__ biasL,
    const float* __restrict__ compL) {
    int tid  = threadIdx.x;
    int lane = tid & 31;
    int sub  = tid >> 5;
    int g    = blockIdx.x * 8 + sub;   // 1024 blocks * 8 = 8192 groups
    float w0[IN], w1[IN], wr[IN];
#pragma unroll
    for (int i = 0; i < IN; i++) {
        w0[i] = basis[i * 32 + lane];
        w1[i] = basis[IN * 32 + i * 32 + lane];
        wr[i] = root[i * 32 + lane];
    }
    float c0[R_REL], c1[R_REL];
#pragma unroll
    for (int r = 0; r < R_REL; r++) {
        c0[r] = compL[r * NBASIS + 0];
        c1[r] = compL[r * NBASIS + 1];
    }
    float bv = biasL[lane];
    for (int n = g; n < N_NODES; n += 8192) {
        float hn = (lane < IN) ? h_in[n * IN + lane] : 0.f;
        float a0 = 0.f, a1 = 0.f, ar = bv;
#pragma unroll
        for (int i = 0; i < IN; i++) {
            float v = __shfl(hn, i, 32);
            a0 += v * w0[i];
            a1 += v * w1[i];
            ar += v * wr[i];
        }
#pragma unroll
        for (int r = 0; r < R_REL; r++)
            y5[(size_t)r * N_NODES * 32 + n * 32 + lane] = f2bf(c0[r] * a0 + c1[r] * a1);
        h_io[n * 32 + lane] = ar;
    }
}

// ---------------- edge aggregation: h[n] = tanh(h[n] + sum nv*y5[et][src]) -

__global__ __launch_bounds__(256) void k_edge(
    const unsigned short* __restrict__ y5, float* __restrict__ h,
    const int2* __restrict__ packed, const int* __restrict__ off) {
    int tid  = threadIdx.x;
    int lane = tid & 31;
    int sub  = tid >> 5;
    int part  = blockIdx.x & 7;
    int local = (blockIdx.x >> 3) * 8 + sub;
    if (local >= PART_SZ) return;
    int n = part * PART_SZ + local;

    float acc = h[n * 32 + lane];
    int e0 = off[n], e1 = off[n + 1];
    for (int base = e0; base < e1; base += 32) {
        int idx = base + lane;
        bool vld = idx < e1;
        int2 pk  = vld ? packed[idx] : make_int2(0, 0);
        int   m  = pk.x;
        float nv = __int_as_float(pk.y);   // 0 bits -> 0.0f for pad lanes
        int kmax = e1 - base;
        if (kmax > 32) kmax = 32;
        int kk = (kmax + 7) & ~7;
        for (int j = 0; j < kk; j += 8) {
            int m0 = __shfl(m, j + 0, 32), m1 = __shfl(m, j + 1, 32);
            int m2 = __shfl(m, j + 2, 32), m3 = __shfl(m, j + 3, 32);
            int m4 = __shfl(m, j + 4, 32), m5 = __shfl(m, j + 5, 32);
            int m6 = __shfl(m, j + 6, 32), m7 = __shfl(m, j + 7, 32);
            unsigned r0 = ((unsigned)m0 >> 20) * N_NODES + (m0 & 0xFFFFF);
            unsigned r1 = ((unsigned)m1 >> 20) * N_NODES + (m1 & 0xFFFFF);
            unsigned r2 = ((unsigned)m2 >> 20) * N_NODES + (m2 & 0xFFFFF);
            unsigned r3 = ((unsigned)m3 >> 20) * N_NODES + (m3 & 0xFFFFF);
            unsigned r4 = ((unsigned)m4 >> 20) * N_NODES + (m4 & 0xFFFFF);
            unsigned r5 = ((unsigned)m5 >> 20) * N_NODES + (m5 & 0xFFFFF);
            unsigned r6 = ((unsigned)m6 >> 20) * N_NODES + (m6 & 0xFFFFF);
            unsigned r7 = ((unsigned)m7 >> 20) * N_NODES + (m7 & 0xFFFFF);
            unsigned short u0 = y5[(size_t)r0 * 32 + lane];
            unsigned short u1 = y5[(size_t)r1 * 32 + lane];
            unsigned short u2 = y5[(size_t)r2 * 32 + lane];
            unsigned short u3 = y5[(size_t)r3 * 32 + lane];
            unsigned short u4 = y5[(size_t)r4 * 32 + lane];
            unsigned short u5 = y5[(size_t)r5 * 32 + lane];
            unsigned short u6 = y5[(size_t)r6 * 32 + lane];
            unsigned short u7 = y5[(size_t)r7 * 32 + lane];
            float v0 = __shfl(nv, j + 0, 32), v1 = __shfl(nv, j + 1, 32);
            float v2 = __shfl(nv, j + 2, 32), v3 = __shfl(nv, j + 3, 32);
            float v4 = __shfl(nv, j + 4, 32), v5 = __shfl(nv, j + 5, 32);
            float v6 = __shfl(nv, j + 6, 32), v7 = __shfl(nv, j + 7, 32);
            acc += v0 * __uint_as_float((unsigned)u0 << 16);
            acc += v1 * __uint_as_float((unsigned)u1 << 16);
            acc += v2 * __uint_as_float((unsigned)u2 << 16);
            acc += v3 * __uint_as_float((unsigned)u3 << 16);
            acc += v4 * __uint_as_float((unsigned)u4 << 16);
            acc += v5 * __uint_as_float((unsigned)u5 << 16);
            acc += v6 * __uint_as_float((unsigned)u6 << 16);
            acc += v7 * __uint_as_float((unsigned)u7 << 16);
        }
    }
    h[n * 32 + lane] = tanhf(acc);
}

// ---------------- start-node row save + MLP head ----------------

__global__ void k_save(const float* __restrict__ h, const int* __restrict__ start,
                       float* __restrict__ sav) {
    int t = blockIdx.x * blockDim.x + threadIdx.x;
    if (t < B_START * 32) {
        int b = t >> 5, ln = t & 31;
        sav[t] = h[start[b] * 32 + ln];
    }
}

__global__ __launch_bounds__(128) void k_mlp(
    const float* __restrict__ sav, const float* __restrict__ w1,
    const float* __restrict__ b1, const float* __restrict__ w2,
    const float* __restrict__ b2, float* __restrict__ out) {
    __shared__ float cvec[128];
    __shared__ float hb[128];
    __shared__ float lg[8];
    int b = blockIdx.x, t = threadIdx.x;
    cvec[t] = sav[(t >> 5) * (B_START * 32) + b * 32 + (t & 31)];
    __syncthreads();
    float a = b1[t];
#pragma unroll 8
    for (int k = 0; k < 128; k++) a += cvec[k] * w1[k * 128 + t];
    hb[t] = fmaxf(a, 0.f);
    __syncthreads();
    if (t < 5) {
        float a2 = b2[t];
        for (int k = 0; k < 128; k++) a2 += hb[k] * w2[k * 5 + t];
        lg[t] = a2;
    }
    __syncthreads();
    if (t < 5) {
        float m = lg[0];
        for (int j = 1; j < 5; j++) m = fmaxf(m, lg[j]);
        float s = 0.f;
        for (int j = 0; j < 5; j++) s += expf(lg[j] - m);
        out[b * 5 + t] = lg[t] - m - logf(s);
    }
}

// ---------------- launch ----------------

extern "C" void kernel_launch(void* const* d_in, const int* in_sizes, int n_in,
                              void* d_out, int out_size, void* d_ws, size_t ws_size,
                              hipStream_t stream) {
    const float* x      = (const float*)d_in[0];
    const int*   ei     = (const int*)d_in[1];
    const int*   etype  = (const int*)d_in[2];
    const int*   start  = (const int*)d_in[3];
    const float* basis0 = (const float*)d_in[4];
    const float* comp0  = (const float*)d_in[5];
    const float* root0  = (const float*)d_in[6];
    const float* bias0  = (const float*)d_in[7];
    const float* basis  = (const float*)d_in[8];
    const float* comp   = (const float*)d_in[9];
    const float* root   = (const float*)d_in[10];
    const float* bias   = (const float*)d_in[11];
    const float* w1     = (const float*)d_in[12];
    const float* b1     = (const float*)d_in[13];
    const float* w2     = (const float*)d_in[14];
    const float* b2     = (const float*)d_in[15];
    float* out = (float*)d_out;

    char* p = (char*)d_ws;
    auto alloc = [&](size_t bytes) -> void* {
        void* r = (void*)p;
        p += (bytes + 255) & ~(size_t)255;
        return r;
    };
    int*            off    = (int*)alloc((N_NODES + 1) * 4);
    int*            cur    = (int*)alloc(N_NODES * 4);
    int*            cnt    = (int*)alloc((N_NODES * R_REL + 8) * 4);  // +8 = gcur
    int*            gcur   = cnt + N_NODES * R_REL;
    int*            bhist  = (int*)alloc(8 * NB_BIN * 4);
    int2*           arena  = (int2*)alloc((size_t)8 * ARENA_CAP * 8);
    int2*           packed = (int2*)alloc((size_t)N_EDGES * 8);
    int*            bsum   = (int*)alloc(512 * 4);
    float*          normf  = (float*)alloc(N_NODES * R_REL * 4);
    float*          h      = (float*)alloc((size_t)N_NODES * 32 * 4);
    unsigned short* y5     = (unsigned short*)alloc((size_t)R_REL * N_NODES * 32 * 2);
    float*          sav    = (float*)alloc(4 * B_START * 32 * 4);

    int nbScan = (N_NODES + 255) / 256;  // 391

    k_zero_int<<<(N_NODES * R_REL + 255) / 256, 256, 0, stream>>>(cnt, N_NODES * R_REL);
    k_cnt8<<<NB_BIN, 256, 0, stream>>>(ei, bhist);
    k_scan8<<<8, 256, 0, stream>>>(bhist, gcur);
    k_scat8<<<NB_BIN, 256, 0, stream>>>(ei, etype, bhist, arena);
    k_hist_p<<<8 * 104, 256, 0, stream>>>(arena, gcur, cnt);
    k_scan1<<<nbScan, 256, 0, stream>>>(cnt, off, bsum, normf);
    k_scan2<<<1, 512, 0, stream>>>(bsum, nbScan);
    k_scan3<<<nbScan, 256, 0, stream>>>(off, cur, bsum);
    k_fill_p<<<8 * 104, 256, 0, stream>>>(arena, gcur, cur, packed, normf);

    int nbEdge = 8 * ((PART_SZ + 7) / 8);  // 12504 blocks
    // layer 0 (in=4)
    k_xform<4><<<1024, 256, 0, stream>>>(x, h, y5, basis0, root0, bias0, comp0);
    k_edge<<<nbEdge, 256, 0, stream>>>(y5, h, packed, off);
    k_save<<<64, 256, 0, stream>>>(h, start, sav);
    // layers 1..3 (in=32)
    for (int l = 0; l < 3; l++) {
        k_xform<32><<<1024, 256, 0, stream>>>(h, h, y5,
                                              basis + (size_t)l * 2048,
                                              root + (size_t)l * 1024,
                                              bias + l * 32,
                                              comp + l * 10);
        k_edge<<<nbEdge, 256, 0, stream>>>(y5, h, packed, off);
        k_save<<<64, 256, 0, stream>>>(h, start, sav + (l + 1) * 16384);
    }

    k_mlp<<<B_START, 128, 0, stream>>>(sav, w1, b1, w2, b2, out);
}

// Round 9
// 402.154 us; speedup vs baseline: 6.8712x; 1.3123x over previous
//
#include <hip/hip_runtime.h>
#include <cstdint>

#define N_NODES 100000
#define N_EDGES 1600000
#define R_REL   5
#define NBASIS  2
#define B_START 512
#define PART_SZ 12500     // 8 * 12500 = 100000 (k_edge swizzle)
#define NBUCK   256
#define BUCK_SZ 391       // 256 * 391 = 100096 >= 100000
#define EPB     6250      // edges per block in cnt/scat (256 * 6250 = 1.6M)
#define STAGE_CAP 7000    // bucket edge-count mean 6256, sd ~79 -> 9.4 sigma

__device__ __forceinline__ unsigned short f2bf(float f) {
    unsigned u = __float_as_uint(f);
    unsigned r = (u + 0x7FFF + ((u >> 16) & 1)) >> 16;  // RNE
    return (unsigned short)r;
}

// ---------------- scatter-free CSR build ----------------

// Pass A: per-block 256-bucket histogram (LDS), coalesced table write.
// bhist layout: [block][bucket] so pass B reads bucket-major coalesced.
__global__ __launch_bounds__(256) void k_cntb(
    const int* __restrict__ ei, int* __restrict__ bhist) {
    __shared__ int lh[NBUCK];
    int tid = threadIdx.x;
    lh[tid] = 0;
    __syncthreads();
    int base = blockIdx.x * EPB;
    for (int j = tid; j < EPB; j += 256) {
        int dst = ei[N_EDGES + base + j];
        atomicAdd(&lh[dst / BUCK_SZ], 1);
    }
    __syncthreads();
    bhist[blockIdx.x * NBUCK + tid] = lh[tid];
}

// Pass B: single block; thread b owns bucket b. Sweep1: bucket totals ->
// block-scan -> bucket bases. Sweep2: rewrite bhist as running prefix
// (per-(block,bucket) global write base). 8-deep unroll hides latency chain.
__global__ __launch_bounds__(256) void k_scanb(
    int* __restrict__ bhist, int* __restrict__ bbase) {
    int b = threadIdx.x;
    int tot = 0;
    for (int i = 0; i < NBUCK; i += 8) {
        int v0 = bhist[(i + 0) * NBUCK + b], v1 = bhist[(i + 1) * NBUCK + b];
        int v2 = bhist[(i + 2) * NBUCK + b], v3 = bhist[(i + 3) * NBUCK + b];
        int v4 = bhist[(i + 4) * NBUCK + b], v5 = bhist[(i + 5) * NBUCK + b];
        int v6 = bhist[(i + 6) * NBUCK + b], v7 = bhist[(i + 7) * NBUCK + b];
        tot += v0 + v1 + v2 + v3 + v4 + v5 + v6 + v7;
    }
    __shared__ int s[NBUCK];
    s[b] = tot;
    __syncthreads();
    for (int o = 1; o < NBUCK; o <<= 1) {
        int v = (b >= o) ? s[b - o] : 0;
        __syncthreads();
        s[b] += v;
        __syncthreads();
    }
    int base = s[b] - tot;  // exclusive
    bbase[b] = base;
    if (b == NBUCK - 1) bbase[NBUCK] = s[NBUCK - 1];  // == N_EDGES
    int run = base;
    for (int i = 0; i < NBUCK; i += 8) {
        int v0 = bhist[(i + 0) * NBUCK + b], v1 = bhist[(i + 1) * NBUCK + b];
        int v2 = bhist[(i + 2) * NBUCK + b], v3 = bhist[(i + 3) * NBUCK + b];
        int v4 = bhist[(i + 4) * NBUCK + b], v5 = bhist[(i + 5) * NBUCK + b];
        int v6 = bhist[(i + 6) * NBUCK + b], v7 = bhist[(i + 7) * NBUCK + b];
        bhist[(i + 0) * NBUCK + b] = run; run += v0;
        bhist[(i + 1) * NBUCK + b] = run; run += v1;
        bhist[(i + 2) * NBUCK + b] = run; run += v2;
        bhist[(i + 3) * NBUCK + b] = run; run += v3;
        bhist[(i + 4) * NBUCK + b] = run; run += v4;
        bhist[(i + 5) * NBUCK + b] = run; run += v5;
        bhist[(i + 6) * NBUCK + b] = run; run += v6;
        bhist[(i + 7) * NBUCK + b] = run; run += v7;
    }
}

// Pass C: deterministic bucket scatter. Per block per bucket ~24 contiguous
// 4B records (run-clustered -> line-dense writes, no global atomics).
// record = src | et<<17 | dst_local<<20
__global__ __launch_bounds__(256) void k_scat(
    const int* __restrict__ ei, const int* __restrict__ et,
    const int* __restrict__ bhist, int* __restrict__ arena) {
    __shared__ int lc[NBUCK];
    int tid = threadIdx.x;
    lc[tid] = bhist[blockIdx.x * NBUCK + tid];
    __syncthreads();
    int base = blockIdx.x * EPB;
    for (int j = tid; j < EPB; j += 256) {
        int e   = base + j;
        int src = ei[e];
        int dst = ei[N_EDGES + e];
        int t   = et[e];
        int bk  = dst / BUCK_SZ;
        int dl  = dst - bk * BUCK_SZ;
        int pos = atomicAdd(&lc[bk], 1);
        arena[pos] = src | (t << 17) | (dl << 20);
    }
}

// Pass D: one block per bucket. Bucket edges are contiguous in arena.
// All counting/offsets/ordering in LDS; every global write coalesced.
__global__ __launch_bounds__(256) void k_build(
    const int* __restrict__ arena, const int* __restrict__ bbase,
    int* __restrict__ off, int* __restrict__ pk_m, float* __restrict__ pk_nv) {
    __shared__ int deg5[BUCK_SZ * R_REL];
    __shared__ int loff[BUCK_SZ + 1];
    __shared__ int cur[BUCK_SZ];
    __shared__ int stg[STAGE_CAP];
    int b = blockIdx.x, tid = threadIdx.x;
    int base = bbase[b], end = bbase[b + 1];
    int count = end - base;
    for (int i = tid; i < BUCK_SZ * R_REL; i += 256) deg5[i] = 0;
    __syncthreads();
    for (int i = tid; i < count; i += 256) {
        int r  = arena[base + i];
        int dl = ((unsigned)r) >> 20;
        int t  = (r >> 17) & 7;
        atomicAdd(&deg5[dl * R_REL + t], 1);
    }
    __syncthreads();
    if (tid == 0) {
        int run = 0;
        for (int dl = 0; dl < BUCK_SZ; dl++) {
            loff[dl] = run;
            run += deg5[dl * R_REL + 0] + deg5[dl * R_REL + 1] +
                   deg5[dl * R_REL + 2] + deg5[dl * R_REL + 3] +
                   deg5[dl * R_REL + 4];
        }
        loff[BUCK_SZ] = run;
    }
    __syncthreads();
    for (int dl = tid; dl < BUCK_SZ; dl += 256) {
        int n = b * BUCK_SZ + dl;
        if (n < N_NODES) off[n] = base + loff[dl];
        cur[dl] = loff[dl];
    }
    if (b == NBUCK - 1 && tid == 0) off[N_NODES] = N_EDGES;
    __syncthreads();
    for (int i = tid; i < count; i += 256) {
        int r  = arena[base + i];
        int dl = ((unsigned)r) >> 20;
        int rk = atomicAdd(&cur[dl], 1);
        if (rk < STAGE_CAP) stg[rk] = r;
    }
    __syncthreads();
    for (int i = tid; i < count; i += 256) {
        int r   = stg[i < STAGE_CAP ? i : STAGE_CAP - 1];
        int src = r & 0x1FFFF;
        int t   = (r >> 17) & 7;
        int dl  = ((unsigned)r) >> 20;
        int c   = deg5[dl * R_REL + t];
        pk_m[base + i]  = src | (t << 20);
        pk_nv[base + i] = 1.0f / (float)(c > 0 ? c : 1);
    }
}

// ---------------- per-layer node transform ---------------------------------
// y5[r][n][c] = bf16( comp[r,0]*(h@B0) + comp[r,1]*(h@B1) )   (5 planes)
// h := h@root + bias   (in-place per-row, race-free)

template <int IN>
__global__ __launch_bounds__(256) void k_xform(
    const float* __restrict__ h_in, float* __restrict__ h_io,
    unsigned short* __restrict__ y5, const float* __restrict__ basis,
    const float* __restrict__ root, const float* __restrict__ biasL,
    const float* __restrict__ compL) {
    int tid  = threadIdx.x;
    int lane = tid & 31;
    int sub  = tid >> 5;
    int g    = blockIdx.x * 8 + sub;   // 1024 blocks * 8 = 8192 groups
    float w0[IN], w1[IN], wr[IN];
#pragma unroll
    for (int i = 0; i < IN; i++) {
        w0[i] = basis[i * 32 + lane];
        w1[i] = basis[IN * 32 + i * 32 + lane];
        wr[i] = root[i * 32 + lane];
    }
    float c0[R_REL], c1[R_REL];
#pragma unroll
    for (int r = 0; r < R_REL; r++) {
        c0[r] = compL[r * NBASIS + 0];
        c1[r] = compL[r * NBASIS + 1];
    }
    float bv = biasL[lane];
    for (int n = g; n < N_NODES; n += 8192) {
        float hn = (lane < IN) ? h_in[n * IN + lane] : 0.f;
        float a0 = 0.f, a1 = 0.f, ar = bv;
#pragma unroll
        for (int i = 0; i < IN; i++) {
            float v = __shfl(hn, i, 32);
            a0 += v * w0[i];
            a1 += v * w1[i];
            ar += v * wr[i];
        }
#pragma unroll
        for (int r = 0; r < R_REL; r++)
            y5[(size_t)r * N_NODES * 32 + n * 32 + lane] = f2bf(c0[r] * a0 + c1[r] * a1);
        h_io[n * 32 + lane] = ar;
    }
}

// ---------------- edge aggregation: h[n] = tanh(h[n] + sum nv*y5[et][src]) -

__global__ __launch_bounds__(256) void k_edge(
    const unsigned short* __restrict__ y5, float* __restrict__ h,
    const int* __restrict__ pk_m, const float* __restrict__ pk_nv,
    const int* __restrict__ off) {
    int tid  = threadIdx.x;
    int lane = tid & 31;
    int sub  = tid >> 5;
    int part  = blockIdx.x & 7;
    int local = (blockIdx.x >> 3) * 8 + sub;
    if (local >= PART_SZ) return;
    int n = part * PART_SZ + local;

    float acc = h[n * 32 + lane];
    int e0 = off[n], e1 = off[n + 1];
    for (int base = e0; base < e1; base += 32) {
        int idx = base + lane;
        bool vld = idx < e1;
        int   m  = vld ? pk_m[idx] : 0;
        float nv = vld ? pk_nv[idx] : 0.f;
        int kmax = e1 - base;
        if (kmax > 32) kmax = 32;
        int kk = (kmax + 7) & ~7;
        for (int j = 0; j < kk; j += 8) {
            int m0 = __shfl(m, j + 0, 32), m1 = __shfl(m, j + 1, 32);
            int m2 = __shfl(m, j + 2, 32), m3 = __shfl(m, j + 3, 32);
            int m4 = __shfl(m, j + 4, 32), m5 = __shfl(m, j + 5, 32);
            int m6 = __shfl(m, j + 6, 32), m7 = __shfl(m, j + 7, 32);
            unsigned r0 = ((unsigned)m0 >> 20) * N_NODES + (m0 & 0xFFFFF);
            unsigned r1 = ((unsigned)m1 >> 20) * N_NODES + (m1 & 0xFFFFF);
            unsigned r2 = ((unsigned)m2 >> 20) * N_NODES + (m2 & 0xFFFFF);
            unsigned r3 = ((unsigned)m3 >> 20) * N_NODES + (m3 & 0xFFFFF);
            unsigned r4 = ((unsigned)m4 >> 20) * N_NODES + (m4 & 0xFFFFF);
            unsigned r5 = ((unsigned)m5 >> 20) * N_NODES + (m5 & 0xFFFFF);
            unsigned r6 = ((unsigned)m6 >> 20) * N_NODES + (m6 & 0xFFFFF);
            unsigned r7 = ((unsigned)m7 >> 20) * N_NODES + (m7 & 0xFFFFF);
            unsigned short u0 = y5[(size_t)r0 * 32 + lane];
            unsigned short u1 = y5[(size_t)r1 * 32 + lane];
            unsigned short u2 = y5[(size_t)r2 * 32 + lane];
            unsigned short u3 = y5[(size_t)r3 * 32 + lane];
            unsigned short u4 = y5[(size_t)r4 * 32 + lane];
            unsigned short u5 = y5[(size_t)r5 * 32 + lane];
            unsigned short u6 = y5[(size_t)r6 * 32 + lane];
            unsigned short u7 = y5[(size_t)r7 * 32 + lane];
            float v0 = __shfl(nv, j + 0, 32), v1 = __shfl(nv, j + 1, 32);
            float v2 = __shfl(nv, j + 2, 32), v3 = __shfl(nv, j + 3, 32);
            float v4 = __shfl(nv, j + 4, 32), v5 = __shfl(nv, j + 5, 32);
            float v6 = __shfl(nv, j + 6, 32), v7 = __shfl(nv, j + 7, 32);
            acc += v0 * __uint_as_float((unsigned)u0 << 16);
            acc += v1 * __uint_as_float((unsigned)u1 << 16);
            acc += v2 * __uint_as_float((unsigned)u2 << 16);
            acc += v3 * __uint_as_float((unsigned)u3 << 16);
            acc += v4 * __uint_as_float((unsigned)u4 << 16);
            acc += v5 * __uint_as_float((unsigned)u5 << 16);
            acc += v6 * __uint_as_float((unsigned)u6 << 16);
            acc += v7 * __uint_as_float((unsigned)u7 << 16);
        }
    }
    h[n * 32 + lane] = tanhf(acc);
}

// ---------------- start-node row save + MLP head ----------------

__global__ void k_save(const float* __restrict__ h, const int* __restrict__ start,
                       float* __restrict__ sav) {
    int t = blockIdx.x * blockDim.x + threadIdx.x;
    if (t < B_START * 32) {
        int b = t >> 5, ln = t & 31;
        sav[t] = h[start[b] * 32 + ln];
    }
}

__global__ __launch_bounds__(128) void k_mlp(
    const float* __restrict__ sav, const float* __restrict__ w1,
    const float* __restrict__ b1, const float* __restrict__ w2,
    const float* __restrict__ b2, float* __restrict__ out) {
    __shared__ float cvec[128];
    __shared__ float hb[128];
    __shared__ float lg[8];
    int b = blockIdx.x, t = threadIdx.x;
    cvec[t] = sav[(t >> 5) * (B_START * 32) + b * 32 + (t & 31)];
    __syncthreads();
    float a = b1[t];
#pragma unroll 8
    for (int k = 0; k < 128; k++) a += cvec[k] * w1[k * 128 + t];
    hb[t] = fmaxf(a, 0.f);
    __syncthreads();
    if (t < 5) {
        float a2 = b2[t];
        for (int k = 0; k < 128; k++) a2 += hb[k] * w2[k * 5 + t];
        lg[t] = a2;
    }
    __syncthreads();
    if (t < 5) {
        float m = lg[0];
        for (int j = 1; j < 5; j++) m = fmaxf(m, lg[j]);
        float s = 0.f;
        for (int j = 0; j < 5; j++) s += expf(lg[j] - m);
        out[b * 5 + t] = lg[t] - m - logf(s);
    }
}

// ---------------- launch ----------------

extern "C" void kernel_launch(void* const* d_in, const int* in_sizes, int n_in,
                              void* d_out, int out_size, void* d_ws, size_t ws_size,
                              hipStream_t stream) {
    const float* x      = (const float*)d_in[0];
    const int*   ei     = (const int*)d_in[1];
    const int*   etype  = (const int*)d_in[2];
    const int*   start  = (const int*)d_in[3];
    const float* basis0 = (const float*)d_in[4];
    const float* comp0  = (const float*)d_in[5];
    const float* root0  = (const float*)d_in[6];
    const float* bias0  = (const float*)d_in[7];
    const float* basis  = (const float*)d_in[8];
    const float* comp   = (const float*)d_in[9];
    const float* root   = (const float*)d_in[10];
    const float* bias   = (const float*)d_in[11];
    const float* w1     = (const float*)d_in[12];
    const float* b1     = (const float*)d_in[13];
    const float* w2     = (const float*)d_in[14];
    const float* b2     = (const float*)d_in[15];
    float* out = (float*)d_out;

    char* p = (char*)d_ws;
    auto alloc = [&](size_t bytes) -> void* {
        void* r = (void*)p;
        p += (bytes + 255) & ~(size_t)255;
        return r;
    };
    int*            off   = (int*)alloc((N_NODES + 1) * 4);
    int*            bhist = (int*)alloc((size_t)NBUCK * NBUCK * 4);
    int*            bbase = (int*)alloc((NBUCK + 1) * 4);
    int*            arena = (int*)alloc((size_t)N_EDGES * 4);
    int*            pk_m  = (int*)alloc((size_t)N_EDGES * 4);
    float*          pk_nv = (float*)alloc((size_t)N_EDGES * 4);
    float*          h     = (float*)alloc((size_t)N_NODES * 32 * 4);
    unsigned short* y5    = (unsigned short*)alloc((size_t)R_REL * N_NODES * 32 * 2);
    float*          sav   = (float*)alloc(4 * B_START * 32 * 4);

    k_cntb<<<NBUCK, 256, 0, stream>>>(ei, bhist);
    k_scanb<<<1, 256, 0, stream>>>(bhist, bbase);
    k_scat<<<NBUCK, 256, 0, stream>>>(ei, etype, bhist, arena);
    k_build<<<NBUCK, 256, 0, stream>>>(arena, bbase, off, pk_m, pk_nv);

    int nbEdge = 8 * ((PART_SZ + 7) / 8);  // 12504 blocks
    // layer 0 (in=4)
    k_xform<4><<<1024, 256, 0, stream>>>(x, h, y5, basis0, root0, bias0, comp0);
    k_edge<<<nbEdge, 256, 0, stream>>>(y5, h, pk_m, pk_nv, off);
    k_save<<<64, 256, 0, stream>>>(h, start, sav);
    // layers 1..3 (in=32)
    for (int l = 0; l < 3; l++) {
        k_xform<32><<<1024, 256, 0, stream>>>(h, h, y5,
                                              basis + (size_t)l * 2048,
                                              root + (size_t)l * 1024,
                                              bias + l * 32,
                                              comp + l * 10);
        k_edge<<<nbEdge, 256, 0, stream>>>(y5, h, pk_m, pk_nv, off);
        k_save<<<64, 256, 0, stream>>>(h, start, sav + (l + 1) * 16384);
    }

    k_mlp<<<B_START, 128, 0, stream>>>(sav, w1, b1, w2, b2, out);
}